// Round 1
// baseline (733.237 us; speedup 1.0000x reference)
//
#include <hip/hip_runtime.h>

#define HH 16
#define DHH 64
#define BB 4
#define SS 2048
#define DD 1024

typedef __attribute__((ext_vector_type(8))) short short8;
typedef __attribute__((ext_vector_type(4))) float f32x4;
typedef __attribute__((ext_vector_type(4))) unsigned short u16x4;

__device__ __forceinline__ unsigned short f2bf(float f) {
  union { float f; unsigned int u; } v; v.f = f;
  unsigned int r = v.u + 0x7fffu + ((v.u >> 16) & 1u);
  return (unsigned short)(r >> 16);
}

// ---------------------------------------------------------------------------
// Projection GEMM: out[m][n] = sum_k X[m][k] * W[n][k] + bias[n]
// X: (8192, 1024) fp32 row-major (m = b*2048 + s)
// W: (1024, 1024) fp32 row-major (row n = output feature)
// mode 0/1: write bf16 (B,H,S,DH);  mode 2: write bf16 (B,H,DH,S) (V^T)
// 128x128 tile, BK=32, 4 waves (2x2 of 64x64), mfma 16x16x32 bf16.
// LDS rows padded to 40 elements (80 B) to break bank conflicts.
// ---------------------------------------------------------------------------
__global__ __launch_bounds__(256) void proj_kernel(
    const float* __restrict__ X, const float* __restrict__ W,
    const float* __restrict__ bias, unsigned short* __restrict__ out,
    int mode)
{
  __shared__ unsigned short As[128 * 40];
  __shared__ unsigned short Bs[128 * 40];

  const int t    = threadIdx.x;
  const int m0   = blockIdx.x * 128;
  const int n0   = blockIdx.y * 128;
  const int rowA = t >> 3;          // 0..31
  const int kc   = (t & 7) * 4;     // 0..28
  const int lane = t & 63;
  const int wid  = t >> 6;
  const int wm   = (wid >> 1) * 64;
  const int wn   = (wid & 1) * 64;
  const int g    = lane >> 4;
  const int c    = lane & 15;

  f32x4 acc[4][4];
#pragma unroll
  for (int i = 0; i < 4; ++i)
#pragma unroll
    for (int j = 0; j < 4; ++j) acc[i][j] = (f32x4){0.f, 0.f, 0.f, 0.f};

  for (int kt = 0; kt < 32; ++kt) {
    __syncthreads();
#pragma unroll
    for (int p = 0; p < 4; ++p) {
      const int r = p * 32 + rowA;
      const float4 xa = *reinterpret_cast<const float4*>(
          X + (size_t)(m0 + r) * DD + kt * 32 + kc);
      const float4 wb = *reinterpret_cast<const float4*>(
          W + (size_t)(n0 + r) * DD + kt * 32 + kc);
      u16x4 ha = { f2bf(xa.x), f2bf(xa.y), f2bf(xa.z), f2bf(xa.w) };
      u16x4 hb = { f2bf(wb.x), f2bf(wb.y), f2bf(wb.z), f2bf(wb.w) };
      *reinterpret_cast<u16x4*>(&As[r * 40 + kc]) = ha;
      *reinterpret_cast<u16x4*>(&Bs[r * 40 + kc]) = hb;
    }
    __syncthreads();

    short8 a[4], b[4];
#pragma unroll
    for (int mf = 0; mf < 4; ++mf)
      a[mf] = *reinterpret_cast<const short8*>(&As[(wm + mf * 16 + c) * 40 + g * 8]);
#pragma unroll
    for (int nf = 0; nf < 4; ++nf)
      b[nf] = *reinterpret_cast<const short8*>(&Bs[(wn + nf * 16 + c) * 40 + g * 8]);
#pragma unroll
    for (int mf = 0; mf < 4; ++mf)
#pragma unroll
      for (int nf = 0; nf < 4; ++nf)
        acc[mf][nf] = __builtin_amdgcn_mfma_f32_16x16x32_bf16(
            a[mf], b[nf], acc[mf][nf], 0, 0, 0);
  }

  // epilogue: C/D layout col = lane&15, row = (lane>>4)*4 + reg
#pragma unroll
  for (int nf = 0; nf < 4; ++nf) {
    const int col  = n0 + wn + nf * 16 + c;
    const float bv = bias[col];
    const int hcol = col >> 6;
    const int dcol = col & 63;
#pragma unroll
    for (int mf = 0; mf < 4; ++mf) {
      const int row0 = m0 + wm + mf * 16 + g * 4;
      const int bi   = row0 >> 11;       // batch
      const int s0   = row0 & 2047;      // seq pos (4 consecutive, no crossing)
      if (mode < 2) {
        const size_t base = ((size_t)(bi * HH + hcol) * SS + s0) * DHH + dcol;
#pragma unroll
        for (int r = 0; r < 4; ++r)
          out[base + (size_t)r * DHH] = f2bf(acc[mf][nf][r] + bv);
      } else {
        const size_t base = ((size_t)(bi * HH + hcol) * DHH + dcol) * SS + s0;
        u16x4 hb = { f2bf(acc[mf][nf][0] + bv), f2bf(acc[mf][nf][1] + bv),
                     f2bf(acc[mf][nf][2] + bv), f2bf(acc[mf][nf][3] + bv) };
        *reinterpret_cast<u16x4*>(&out[base]) = hb;
      }
    }
  }
}

// ---------------------------------------------------------------------------
// Flash attention, swapped-QK^T form.
// Q,K: bf16 (B,H,S,DH); Vt: bf16 (B,H,DH,S); O: fp32 (B,S,D).
// Block = 4 waves, each wave owns 16 q-rows (one q per lane-column).
// Per 64-key tile: S^T = mfma(K, Q) (lane holds 16 scores of ONE q-row),
// in-lane+2-shfl online softmax (exp2 domain), P^T redistributed to PV
// B-operand layout via 16 packed-bf16 shfls, O^T = mfma(V^T, P^T).
// ---------------------------------------------------------------------------
__global__ __launch_bounds__(256) void attn_kernel(
    const unsigned short* __restrict__ Qb,
    const unsigned short* __restrict__ Kb,
    const unsigned short* __restrict__ Vt,
    float* __restrict__ O)
{
  const int t    = threadIdx.x;
  const int lane = t & 63;
  const int wid  = t >> 6;
  const int g    = lane >> 4;
  const int c    = lane & 15;
  const int bh   = blockIdx.y;
  const int q0   = blockIdx.x * 64 + wid * 16;

  const unsigned short* Qp = Qb + (size_t)bh * SS * DHH;
  const unsigned short* Kp = Kb + (size_t)bh * SS * DHH;
  const unsigned short* Vp = Vt + (size_t)bh * DHH * SS;

  // Q fragments (B operand): lane holds Q[q0+c][d = tt*32 + g*8 + 0..7]
  short8 bq[2];
#pragma unroll
  for (int tt = 0; tt < 2; ++tt)
    bq[tt] = *reinterpret_cast<const short8*>(
        Qp + (size_t)(q0 + c) * DHH + tt * 32 + g * 8);

  float m_run = -1e30f, l_run = 0.f;
  f32x4 oacc[4];
#pragma unroll
  for (int dd = 0; dd < 4; ++dd) oacc[dd] = (f32x4){0.f, 0.f, 0.f, 0.f};

  const float CLOG = 0.125f * 1.4426950408889634f;  // scale * log2(e)

  for (int kk0 = 0; kk0 < SS; kk0 += 64) {
    // QK^T (swapped): sc[f] holds S^T[kk = kk0+f*16+g*4+r][q = q0+c]
    f32x4 sc[4];
#pragma unroll
    for (int f = 0; f < 4; ++f) sc[f] = (f32x4){0.f, 0.f, 0.f, 0.f};
#pragma unroll
    for (int f = 0; f < 4; ++f)
#pragma unroll
      for (int tt = 0; tt < 2; ++tt) {
        short8 ak = *reinterpret_cast<const short8*>(
            Kp + (size_t)(kk0 + f * 16 + c) * DHH + tt * 32 + g * 8);
        sc[f] = __builtin_amdgcn_mfma_f32_16x16x32_bf16(ak, bq[tt], sc[f], 0, 0, 0);
      }

    // online softmax for this lane's q-row (16 scores in-lane, 4 lane groups)
    float mloc = -1e30f;
#pragma unroll
    for (int f = 0; f < 4; ++f)
#pragma unroll
      for (int r = 0; r < 4; ++r) mloc = fmaxf(mloc, sc[f][r]);
    mloc = fmaxf(mloc, __shfl_xor(mloc, 16));
    mloc = fmaxf(mloc, __shfl_xor(mloc, 32));
    const float m_new = fmaxf(m_run, mloc * CLOG);
    const float alpha = exp2f(m_run - m_new);

    float p[16];
    float rs = 0.f;
#pragma unroll
    for (int f = 0; f < 4; ++f)
#pragma unroll
      for (int r = 0; r < 4; ++r) {
        const float pv = exp2f(sc[f][r] * CLOG - m_new);
        p[f * 4 + r] = pv;
        rs += pv;
      }
    rs += __shfl_xor(rs, 16);
    rs += __shfl_xor(rs, 32);
    l_run = l_run * alpha + rs;
    m_run = m_new;
#pragma unroll
    for (int dd = 0; dd < 4; ++dd) oacc[dd] *= alpha;

    // pack P to bf16 pairs: pp[f*2+r2] = (p[f][2r2+1], p[f][2r2])
    unsigned int pp[8];
#pragma unroll
    for (int f = 0; f < 4; ++f)
#pragma unroll
      for (int r2 = 0; r2 < 2; ++r2)
        pp[f * 2 + r2] = (unsigned)f2bf(p[f * 4 + 2 * r2]) |
                         ((unsigned)f2bf(p[f * 4 + 2 * r2 + 1]) << 16);

    // PV: O^T[d][q] += V^T[d][kk] * P^T[kk][q], two k-steps of 32
#pragma unroll
    for (int tt = 0; tt < 2; ++tt) {
      union { unsigned int u[4]; short8 s; } pb;
#pragma unroll
      for (int j2 = 0; j2 < 4; ++j2) {
        const int gs  = (2 * g + (j2 >> 1)) & 3;
        const int src = c + (gs << 4);
        const unsigned int w0 = (unsigned)__shfl((int)pp[(2 * tt) * 2 + (j2 & 1)], src);
        const unsigned int w1 = (unsigned)__shfl((int)pp[(2 * tt + 1) * 2 + (j2 & 1)], src);
        pb.u[j2] = (g & 2) ? w1 : w0;
      }
#pragma unroll
      for (int dd = 0; dd < 4; ++dd) {
        short8 av = *reinterpret_cast<const short8*>(
            Vp + (size_t)(dd * 16 + c) * SS + kk0 + tt * 32 + g * 8);
        oacc[dd] = __builtin_amdgcn_mfma_f32_16x16x32_bf16(av, pb.s, oacc[dd], 0, 0, 0);
      }
    }
  }

  // epilogue: O^T frag col = q = c, rows d = dd*16 + g*4 + r (r contiguous in D)
  const float inv = 1.f / l_run;
  const int b = bh >> 4, h = bh & 15;
#pragma unroll
  for (int dd = 0; dd < 4; ++dd) {
    f32x4 w = oacc[dd] * inv;
    const size_t idx = ((size_t)(b * SS) + q0 + c) * DD + h * DHH + dd * 16 + g * 4;
    *reinterpret_cast<f32x4*>(O + idx) = w;
  }
}

extern "C" void kernel_launch(void* const* d_in, const int* in_sizes, int n_in,
                              void* d_out, int out_size, void* d_ws, size_t ws_size,
                              hipStream_t stream) {
  (void)in_sizes; (void)n_in; (void)out_size; (void)ws_size;
  const float* Xq = (const float*)d_in[0];
  const float* Xk = (const float*)d_in[1];
  const float* Xv = (const float*)d_in[2];
  const float* WQ = (const float*)d_in[3];
  const float* bQ = (const float*)d_in[4];
  const float* WK = (const float*)d_in[5];
  const float* bK = (const float*)d_in[6];
  const float* WV = (const float*)d_in[7];
  const float* bV = (const float*)d_in[8];
  float* O = (float*)d_out;

  const size_t elems = (size_t)BB * HH * SS * DHH;  // 8.4M, 16 MB bf16 each
  unsigned short* Qb = (unsigned short*)d_ws;
  unsigned short* Kb = Qb + elems;
  unsigned short* Vt = Kb + elems;

  dim3 gproj(64, 8);
  proj_kernel<<<gproj, 256, 0, stream>>>(Xq, WQ, bQ, Qb, 0);
  proj_kernel<<<gproj, 256, 0, stream>>>(Xk, WK, bK, Kb, 1);
  proj_kernel<<<gproj, 256, 0, stream>>>(Xv, WV, bV, Vt, 2);

  attn_kernel<<<dim3(32, 64), 256, 0, stream>>>(Qb, Kb, Vt, O);
}

// Round 2
// 380.274 us; speedup vs baseline: 1.9282x; 1.9282x over previous
//
#include <hip/hip_runtime.h>

#define HH 16
#define DHH 64
#define BB 4
#define SS 2048
#define DD 1024

typedef __attribute__((ext_vector_type(8))) short short8;
typedef __attribute__((ext_vector_type(4))) float f32x4;
typedef __attribute__((ext_vector_type(16))) float f32x16;

__device__ __forceinline__ unsigned short f2bf(float f) {
  union { float f; unsigned int u; } v; v.f = f;
  unsigned int r = v.u + 0x7fffu + ((v.u >> 16) & 1u);
  return (unsigned short)(r >> 16);
}
__device__ __forceinline__ unsigned cvt_pk_bf16(float a, float b) {
  unsigned r;
  asm("v_cvt_pk_bf16_f32 %0, %1, %2" : "=v"(r) : "v"(a), "v"(b));
  return r;
}

// ---------------------------------------------------------------------------
// Projection GEMM: out[m][n] = (sum_k X[m][k] * W[n][k] + bias[n]) * scale
// XCD-swizzled blocks (same-XCD blocks share X/W panels in L2), register
// prefetch of next K-slab, v_cvt_pk_bf16_f32 staging conversion.
// mode 0/1: write bf16 (B,H,S,DH);  mode 2: write bf16 (B,H,DH,S) (V^T)
// ---------------------------------------------------------------------------
__global__ __launch_bounds__(256) void proj_kernel(
    const float* __restrict__ X, const float* __restrict__ W,
    const float* __restrict__ bias, unsigned short* __restrict__ out,
    int mode, float scale)
{
  __shared__ unsigned short As[128 * 40];
  __shared__ unsigned short Bs[128 * 40];

  const int t    = threadIdx.x;
  const int pb   = blockIdx.x;                 // 512 blocks
  const int lb   = (pb & 7) * 64 + (pb >> 3);  // XCD swizzle: 64 per XCD
  const int m0   = (lb >> 3) * 128;
  const int n0   = (lb & 7) * 128;
  const int rowA = t >> 3;          // 0..31
  const int kc   = (t & 7) * 4;     // 0..28
  const int lane = t & 63;
  const int wid  = t >> 6;
  const int wm   = (wid >> 1) * 64;
  const int wn   = (wid & 1) * 64;
  const int g    = lane >> 4;
  const int c    = lane & 15;

  f32x4 acc[4][4];
#pragma unroll
  for (int i = 0; i < 4; ++i)
#pragma unroll
    for (int j = 0; j < 4; ++j) acc[i][j] = (f32x4){0.f, 0.f, 0.f, 0.f};

  float4 xa[4], wb[4];
#pragma unroll
  for (int p4 = 0; p4 < 4; ++p4) {
    const int r = p4 * 32 + rowA;
    xa[p4] = *reinterpret_cast<const float4*>(X + (size_t)(m0 + r) * DD + kc);
    wb[p4] = *reinterpret_cast<const float4*>(W + (size_t)(n0 + r) * DD + kc);
  }

  for (int kt = 0; kt < 32; ++kt) {
    __syncthreads();
#pragma unroll
    for (int p4 = 0; p4 < 4; ++p4) {
      const int r = p4 * 32 + rowA;
      unsigned* da = reinterpret_cast<unsigned*>(&As[r * 40 + kc]);
      unsigned* db = reinterpret_cast<unsigned*>(&Bs[r * 40 + kc]);
      da[0] = cvt_pk_bf16(xa[p4].x, xa[p4].y);
      da[1] = cvt_pk_bf16(xa[p4].z, xa[p4].w);
      db[0] = cvt_pk_bf16(wb[p4].x, wb[p4].y);
      db[1] = cvt_pk_bf16(wb[p4].z, wb[p4].w);
    }
    __syncthreads();
    if (kt < 31) {
#pragma unroll
      for (int p4 = 0; p4 < 4; ++p4) {
        const int r = p4 * 32 + rowA;
        xa[p4] = *reinterpret_cast<const float4*>(
            X + (size_t)(m0 + r) * DD + (kt + 1) * 32 + kc);
        wb[p4] = *reinterpret_cast<const float4*>(
            W + (size_t)(n0 + r) * DD + (kt + 1) * 32 + kc);
      }
    }
    short8 a[4], b[4];
#pragma unroll
    for (int mf = 0; mf < 4; ++mf)
      a[mf] = *reinterpret_cast<const short8*>(&As[(wm + mf * 16 + c) * 40 + g * 8]);
#pragma unroll
    for (int nf = 0; nf < 4; ++nf)
      b[nf] = *reinterpret_cast<const short8*>(&Bs[(wn + nf * 16 + c) * 40 + g * 8]);
#pragma unroll
    for (int mf = 0; mf < 4; ++mf)
#pragma unroll
      for (int nf = 0; nf < 4; ++nf)
        acc[mf][nf] = __builtin_amdgcn_mfma_f32_16x16x32_bf16(
            a[mf], b[nf], acc[mf][nf], 0, 0, 0);
  }

  // epilogue: C/D layout col = lane&15, row = (lane>>4)*4 + reg
#pragma unroll
  for (int nf = 0; nf < 4; ++nf) {
    const int col  = n0 + wn + nf * 16 + c;
    const float bv = bias[col];
    const int hcol = col >> 6;
    const int dcol = col & 63;
#pragma unroll
    for (int mf = 0; mf < 4; ++mf) {
      const int row0 = m0 + wm + mf * 16 + g * 4;
      const int bi   = row0 >> 11;
      const int s0   = row0 & 2047;
      if (mode < 2) {
        const size_t base = ((size_t)(bi * HH + hcol) * SS + s0) * DHH + dcol;
#pragma unroll
        for (int r = 0; r < 4; ++r)
          out[base + (size_t)r * DHH] = f2bf((acc[mf][nf][r] + bv) * scale);
      } else {
        const size_t base = ((size_t)(bi * HH + hcol) * DHH + dcol) * SS + s0;
        unsigned* dp = reinterpret_cast<unsigned*>(out + base);
        dp[0] = cvt_pk_bf16(acc[mf][nf][0] + bv, acc[mf][nf][1] + bv);
        dp[1] = cvt_pk_bf16(acc[mf][nf][2] + bv, acc[mf][nf][3] + bv);
      }
    }
  }
}

// ---------------------------------------------------------------------------
// Flash attention, 32x32x16 MFMA, swapped QK^T (lane owns one q-row's scores).
// Q pre-scaled by 0.125*log2(e) in proj. K/V double-buffered in LDS via
// global_load_lds with XOR-swizzled source chunks; 1 barrier per 64-key tile.
// Block = 4 waves x 32 q-rows = 128 q. Grid XCD-swizzled so all 16 q-blocks
// of one (b,h) share an XCD L2 (K/V = 512KB fits the 4MB L2).
// ---------------------------------------------------------------------------
__global__ __launch_bounds__(256, 4) void attn_kernel(
    const unsigned short* __restrict__ Qb,
    const unsigned short* __restrict__ Kb,
    const unsigned short* __restrict__ Vt,
    float* __restrict__ O)
{
  __shared__ unsigned short sm[16384];  // 2 bufs x (K 8KB + V 8KB)

  const int t    = threadIdx.x;
  const int lane = t & 63;
  const int w    = t >> 6;
  const int h    = lane >> 5;
  const int c5   = lane & 31;
  const int cx   = c5 & 7;

  const int p  = blockIdx.x;                  // 1024 blocks
  const int l  = (p & 7) * 128 + (p >> 3);    // XCD swizzle
  const int bh = l >> 4;
  const int qb = l & 15;
  const int q0 = qb * 128 + w * 32;

  const unsigned short* Qp = Qb + (size_t)bh * SS * DHH;
  const unsigned short* Kp = Kb + (size_t)bh * SS * DHH;
  const unsigned short* Vp = Vt + (size_t)bh * DHH * SS;

  const int srow   = t >> 3;                      // 0..31
  const int schunk = (t & 7) ^ (srow & 7);        // pre-swizzled source chunk

  auto STAGE = [&](int buf, int kt) {
    const int kk0 = kt * 64;
#pragma unroll
    for (int j = 0; j < 2; ++j) {
      const unsigned short* gk = Kp + (size_t)(kk0 + j * 32 + srow) * DHH + schunk * 8;
      const unsigned short* gv = Vp + (size_t)(j * 32 + srow) * SS + kk0 + schunk * 8;
      __builtin_amdgcn_global_load_lds(
          (const __attribute__((address_space(1))) void*)gk,
          (__attribute__((address_space(3))) void*)(sm + buf * 8192 + j * 2048 + w * 512),
          16, 0, 0);
      __builtin_amdgcn_global_load_lds(
          (const __attribute__((address_space(1))) void*)gv,
          (__attribute__((address_space(3))) void*)(sm + buf * 8192 + 4096 + j * 2048 + w * 512),
          16, 0, 0);
    }
  };

  // Q B-frags: lane (h,c5) holds Q[q0+c5][k4*16 + 8h + j]
  short8 bq[4];
#pragma unroll
  for (int k4 = 0; k4 < 4; ++k4)
    bq[k4] = *reinterpret_cast<const short8*>(
        Qp + (size_t)(q0 + c5) * DHH + k4 * 16 + h * 8);

  STAGE(0, 0);

  f32x16 oa0, oa1;
#pragma unroll
  for (int i = 0; i < 16; ++i) { oa0[i] = 0.f; oa1[i] = 0.f; }
  float m_run = -1e30f, l_part = 0.f;

  __syncthreads();

  for (int kt = 0; kt < SS / 64; ++kt) {
    const int buf = kt & 1;
    if (kt + 1 < SS / 64) STAGE(buf ^ 1, kt + 1);

    const unsigned short* Kl = sm + buf * 8192;
    const unsigned short* Vl = Kl + 4096;

    // QK^T: st half = S^T[kk0 + half*32 + crow][q0+c5], crow=(r&3)+8*(r>>2)+4h
    f32x16 st0, st1;
#pragma unroll
    for (int i = 0; i < 16; ++i) { st0[i] = 0.f; st1[i] = 0.f; }
#pragma unroll
    for (int k4 = 0; k4 < 4; ++k4) {
      const int pos = ((2 * k4 + h) ^ cx) * 8;
      short8 ak0 = *reinterpret_cast<const short8*>(Kl + c5 * 64 + pos);
      short8 ak1 = *reinterpret_cast<const short8*>(Kl + (32 + c5) * 64 + pos);
      st0 = __builtin_amdgcn_mfma_f32_32x32x16_bf16(ak0, bq[k4], st0, 0, 0, 0);
      st1 = __builtin_amdgcn_mfma_f32_32x32x16_bf16(ak1, bq[k4], st1, 0, 0, 0);
    }

    // online softmax (scores already in log2 domain via pre-scaled Q)
    float mloc = st0[0];
#pragma unroll
    for (int i = 1; i < 16; ++i) mloc = fmaxf(mloc, st0[i]);
#pragma unroll
    for (int i = 0; i < 16; ++i) mloc = fmaxf(mloc, st1[i]);
    mloc = fmaxf(mloc, __shfl_xor(mloc, 32));

    if (!__all(mloc <= m_run + 11.0f)) {   // defer-max rescale
      const float mn = fmaxf(m_run, mloc);
      const float al = exp2f(m_run - mn);
      l_part *= al;
#pragma unroll
      for (int i = 0; i < 16; ++i) { oa0[i] *= al; oa1[i] *= al; }
      m_run = mn;
    }

#pragma unroll
    for (int i = 0; i < 16; ++i) { st0[i] = exp2f(st0[i] - m_run); l_part += st0[i]; }
#pragma unroll
    for (int i = 0; i < 16; ++i) { st1[i] = exp2f(st1[i] - m_run); l_part += st1[i]; }

    // pack P: pw[M*2+t2] = pair(rows 8M+4h+2t2, +1), M = half*4 + m4
    unsigned pw[16];
#pragma unroll
    for (int m4 = 0; m4 < 4; ++m4)
#pragma unroll
      for (int t2 = 0; t2 < 2; ++t2) {
        pw[m4 * 2 + t2]     = cvt_pk_bf16(st0[m4 * 4 + 2 * t2], st0[m4 * 4 + 2 * t2 + 1]);
        pw[8 + m4 * 2 + t2] = cvt_pk_bf16(st1[m4 * 4 + 2 * t2], st1[m4 * 4 + 2 * t2 + 1]);
      }

    // PV: O^T += V^T * P^T, 4 k-steps of 16
#pragma unroll
    for (int ks = 0; ks < 4; ++ks) {
      union { unsigned u[4]; short8 s8; } pbu;
#pragma unroll
      for (int t2 = 0; t2 < 2; ++t2) {
        const unsigned e  = pw[4 * ks + t2];       // even M = 2ks
        const unsigned o  = pw[4 * ks + 2 + t2];   // odd  M = 2ks+1
        const unsigned ce = (unsigned)__shfl_xor((int)e, 32);
        const unsigned co = (unsigned)__shfl_xor((int)o, 32);
        pbu.u[t2]     = h ? co : e;   // rows 16ks + 8h + {2t2,2t2+1}
        pbu.u[2 + t2] = h ? o  : ce;  // rows 16ks + 8h + 4 + {2t2,2t2+1}
      }
      const int vpos = ((2 * ks + h) ^ cx) * 8;
      short8 av0 = *reinterpret_cast<const short8*>(Vl + c5 * 64 + vpos);
      short8 av1 = *reinterpret_cast<const short8*>(Vl + (32 + c5) * 64 + vpos);
      oa0 = __builtin_amdgcn_mfma_f32_32x32x16_bf16(av0, pbu.s8, oa0, 0, 0, 0);
      oa1 = __builtin_amdgcn_mfma_f32_32x32x16_bf16(av1, pbu.s8, oa1, 0, 0, 0);
    }
    __syncthreads();
  }

  // epilogue: O[b, q0+c5, hd*64 + d], d = dh2*32 + 8*m4 + 4h + r
  const float lt  = l_part + __shfl_xor(l_part, 32);
  const float inv = 1.f / lt;
  const int b = bh >> 4, hd = bh & 15;
  float* Orow = O + ((size_t)(b * SS) + q0 + c5) * DD + hd * DHH;
#pragma unroll
  for (int m4 = 0; m4 < 4; ++m4) {
    f32x4 v0, v1;
#pragma unroll
    for (int r = 0; r < 4; ++r) {
      v0[r] = oa0[m4 * 4 + r] * inv;
      v1[r] = oa1[m4 * 4 + r] * inv;
    }
    *reinterpret_cast<f32x4*>(Orow + m4 * 8 + 4 * h)      = v0;
    *reinterpret_cast<f32x4*>(Orow + 32 + m4 * 8 + 4 * h) = v1;
  }
}

extern "C" void kernel_launch(void* const* d_in, const int* in_sizes, int n_in,
                              void* d_out, int out_size, void* d_ws, size_t ws_size,
                              hipStream_t stream) {
  (void)in_sizes; (void)n_in; (void)out_size; (void)ws_size;
  const float* Xq = (const float*)d_in[0];
  const float* Xk = (const float*)d_in[1];
  const float* Xv = (const float*)d_in[2];
  const float* WQ = (const float*)d_in[3];
  const float* bQ = (const float*)d_in[4];
  const float* WK = (const float*)d_in[5];
  const float* bK = (const float*)d_in[6];
  const float* WV = (const float*)d_in[7];
  const float* bV = (const float*)d_in[8];
  float* O = (float*)d_out;

  const size_t elems = (size_t)BB * HH * SS * DHH;
  unsigned short* Qbuf = (unsigned short*)d_ws;
  unsigned short* Kbuf = Qbuf + elems;
  unsigned short* Vbuf = Kbuf + elems;

  const float CLOG = 0.125f * 1.4426950408889634f;  // 1/sqrt(DH) * log2(e)
  proj_kernel<<<512, 256, 0, stream>>>(Xq, WQ, bQ, Qbuf, 0, CLOG);
  proj_kernel<<<512, 256, 0, stream>>>(Xk, WK, bK, Kbuf, 1, 1.0f);
  proj_kernel<<<512, 256, 0, stream>>>(Xv, WV, bV, Vbuf, 2, 1.0f);

  attn_kernel<<<1024, 256, 0, stream>>>(Qbuf, Kbuf, Vbuf, O);
}

// Round 6
// 324.288 us; speedup vs baseline: 2.2611x; 1.1726x over previous
//
#include <hip/hip_runtime.h>

#define HH 16
#define DHH 64
#define BB 4
#define SS 2048
#define DD 1024
#define XN 8388608   // 8192*1024
#define WN 1048576   // 1024*1024

typedef __attribute__((ext_vector_type(8))) short short8;
typedef __attribute__((ext_vector_type(4))) float f32x4;
typedef __attribute__((ext_vector_type(16))) float f32x16;

__device__ __forceinline__ unsigned short f2bf(float f) {
  union { float f; unsigned int u; } v; v.f = f;
  unsigned int r = v.u + 0x7fffu + ((v.u >> 16) & 1u);
  return (unsigned short)(r >> 16);
}
__device__ __forceinline__ unsigned cvt_pk_bf16(float a, float b) {
  unsigned r;
  asm("v_cvt_pk_bf16_f32 %0, %1, %2" : "=v"(r) : "v"(a), "v"(b));
  return r;
}
__device__ __forceinline__ float fast_exp2(float x) {
  float r;
  asm("v_exp_f32 %0, %1" : "=v"(r) : "v"(x));
  return r;
}
__device__ __forceinline__ float m3(float a, float b, float c) {
  float r;
  asm("v_max3_f32 %0, %1, %2, %3" : "=v"(r) : "v"(a), "v"(b), "v"(c));
  return r;
}
__device__ __forceinline__ void plswap(unsigned& a, unsigned& b) {
  auto r = __builtin_amdgcn_permlane32_swap(a, b, false, false);
  a = r[0]; b = r[1];
}

// ---------------------------------------------------------------------------
// fp32 -> bf16 convert: X (8192x1024) and W (1024x1024) in one launch.
// ---------------------------------------------------------------------------
__global__ __launch_bounds__(256) void conv_kernel(
    const float* __restrict__ X, const float* __restrict__ W,
    unsigned short* __restrict__ Xb, unsigned short* __restrict__ Wb)
{
  const size_t gid = (size_t)blockIdx.x * 256 + threadIdx.x;  // per 8 elems
  const float* src; unsigned short* dst; size_t off;
  if (gid < XN / 8) { src = X; dst = Xb; off = gid * 8; }
  else              { src = W; dst = Wb; off = (gid - XN / 8) * 8; }
  const float4 a = *reinterpret_cast<const float4*>(src + off);
  const float4 b = *reinterpret_cast<const float4*>(src + off + 4);
  unsigned r[4] = { cvt_pk_bf16(a.x, a.y), cvt_pk_bf16(a.z, a.w),
                    cvt_pk_bf16(b.x, b.y), cvt_pk_bf16(b.z, b.w) };
  *reinterpret_cast<uint4*>(dst + off) = *reinterpret_cast<uint4*>(r);
}

// ---------------------------------------------------------------------------
// bf16 projection GEMM (m97 structure): 128x128 tile, BK=64, 4 waves,
// global_load_lds width-16 staging with XOR-swizzled source chunks,
// swizzled ds_read_b128 (2-way conflicts max). XCD-swizzled grid.
// out[m][n] = (sum_k Xb[m][k]*Wb[n][k] + bias[n]) * scale
// mode 0/1: bf16 (B,H,S,DH);  mode 2: bf16 (B,H,DH,S) (V^T)
// ---------------------------------------------------------------------------
__global__ __launch_bounds__(256) void proj_kernel(
    const unsigned short* __restrict__ Xb, const unsigned short* __restrict__ Wb,
    const float* __restrict__ bias, unsigned short* __restrict__ out,
    int mode, float scale)
{
  __shared__ unsigned short As[2][128 * 64];
  __shared__ unsigned short Bs[2][128 * 64];

  const int t    = threadIdx.x;
  const int pb   = blockIdx.x;                 // 512 blocks
  const int lb   = (pb & 7) * 64 + (pb >> 3);  // XCD swizzle
  const int m0   = (lb >> 3) * 128;
  const int n0   = (lb & 7) * 128;
  const int lane = t & 63;
  const int wid  = t >> 6;
  const int wm   = (wid >> 1) * 64;
  const int wn   = (wid & 1) * 64;
  const int g    = lane >> 4;
  const int c    = lane & 15;
  const int cx   = c & 7;

  const int srow = t >> 3;                    // 0..31 within a 4KB issue
  const int sch  = (t & 7) ^ (srow & 7);      // pre-swizzled source chunk

  auto STAGE = [&](int buf, int k0) {
#pragma unroll
    for (int i = 0; i < 4; ++i) {
      const unsigned short* ga = Xb + (size_t)(m0 + i * 32 + srow) * DD + k0 + sch * 8;
      const unsigned short* gb = Wb + (size_t)(n0 + i * 32 + srow) * DD + k0 + sch * 8;
      __builtin_amdgcn_global_load_lds(
          (const __attribute__((address_space(1))) void*)ga,
          (__attribute__((address_space(3))) void*)(&As[buf][0] + i * 2048 + wid * 512),
          16, 0, 0);
      __builtin_amdgcn_global_load_lds(
          (const __attribute__((address_space(1))) void*)gb,
          (__attribute__((address_space(3))) void*)(&Bs[buf][0] + i * 2048 + wid * 512),
          16, 0, 0);
    }
  };

  f32x4 acc[4][4];
#pragma unroll
  for (int i = 0; i < 4; ++i)
#pragma unroll
    for (int j = 0; j < 4; ++j) acc[i][j] = (f32x4){0.f, 0.f, 0.f, 0.f};

  STAGE(0, 0);

  for (int kt = 0; kt < 16; ++kt) {
    const int buf = kt & 1;
    __syncthreads();                       // drains prior stage (vmcnt0) + protects bufs
    if (kt < 15) STAGE(buf ^ 1, (kt + 1) * 64);

    short8 a[4][2], b[4][2];
#pragma unroll
    for (int mf = 0; mf < 4; ++mf) {
      const int row = wm + mf * 16 + c;
#pragma unroll
      for (int ks = 0; ks < 2; ++ks)
        a[mf][ks] = *reinterpret_cast<const short8*>(
            &As[buf][row * 64 + (((ks * 4 + g) ^ cx)) * 8]);
    }
#pragma unroll
    for (int nf = 0; nf < 4; ++nf) {
      const int row = wn + nf * 16 + c;
#pragma unroll
      for (int ks = 0; ks < 2; ++ks)
        b[nf][ks] = *reinterpret_cast<const short8*>(
            &Bs[buf][row * 64 + (((ks * 4 + g) ^ cx)) * 8]);
    }
#pragma unroll
    for (int ks = 0; ks < 2; ++ks)
#pragma unroll
      for (int mf = 0; mf < 4; ++mf)
#pragma unroll
        for (int nf = 0; nf < 4; ++nf)
          acc[mf][nf] = __builtin_amdgcn_mfma_f32_16x16x32_bf16(
              a[mf][ks], b[nf][ks], acc[mf][nf], 0, 0, 0);
  }

  // epilogue: C/D col = lane&15 (N), row = (lane>>4)*4 + reg (M)
#pragma unroll
  for (int nf = 0; nf < 4; ++nf) {
    const int col  = n0 + wn + nf * 16 + c;
    const float bv = bias[col];
    const int hcol = col >> 6;
    const int dcol = col & 63;
#pragma unroll
    for (int mf = 0; mf < 4; ++mf) {
      const int row0 = m0 + wm + mf * 16 + g * 4;
      const int bi   = row0 >> 11;
      const int s0   = row0 & 2047;
      if (mode < 2) {
        const size_t base = ((size_t)(bi * HH + hcol) * SS + s0) * DHH + dcol;
#pragma unroll
        for (int r = 0; r < 4; ++r)
          out[base + (size_t)r * DHH] = f2bf((acc[mf][nf][r] + bv) * scale);
      } else {
        const size_t base = ((size_t)(bi * HH + hcol) * DHH + dcol) * SS + s0;
        unsigned* dp = reinterpret_cast<unsigned*>(out + base);
        dp[0] = cvt_pk_bf16(acc[mf][nf][0] + bv, acc[mf][nf][1] + bv);
        dp[1] = cvt_pk_bf16(acc[mf][nf][2] + bv, acc[mf][nf][3] + bv);
      }
    }
  }
}

// ---------------------------------------------------------------------------
// Flash attention, 32x32x16 MFMA, swapped QK^T. Q pre-scaled by 0.125*log2e.
// VALU-lean softmax: -m_run folded into MFMA C-init (no subs), v_max3 tree,
// raw v_exp_f32, permlane32_swap P-redistribution (no ds_bpermute/cndmask),
// s_setprio around MFMA clusters. m_run starts at 0; rescale ~never fires.
// ---------------------------------------------------------------------------
__global__ __launch_bounds__(256, 4) void attn_kernel(
    const unsigned short* __restrict__ Qb,
    const unsigned short* __restrict__ Kb,
    const unsigned short* __restrict__ Vt,
    float* __restrict__ O)
{
  __shared__ unsigned short sm[16384];  // 2 bufs x (K 8KB + V 8KB)

  const int t    = threadIdx.x;
  const int lane = t & 63;
  const int w    = t >> 6;
  const int h    = lane >> 5;
  const int c5   = lane & 31;
  const int cx   = c5 & 7;

  const int p  = blockIdx.x;                  // 1024 blocks
  const int l  = (p & 7) * 128 + (p >> 3);    // XCD swizzle
  const int bh = l >> 4;
  const int qb = l & 15;
  const int q0 = qb * 128 + w * 32;

  const unsigned short* Qp = Qb + (size_t)bh * SS * DHH;
  const unsigned short* Kp = Kb + (size_t)bh * SS * DHH;
  const unsigned short* Vp = Vt + (size_t)bh * DHH * SS;

  const int srow   = t >> 3;
  const int schunk = (t & 7) ^ (srow & 7);

  auto STAGE = [&](int buf, int kt) {
    const int kk0 = kt * 64;
#pragma unroll
    for (int j = 0; j < 2; ++j) {
      const unsigned short* gk = Kp + (size_t)(kk0 + j * 32 + srow) * DHH + schunk * 8;
      const unsigned short* gv = Vp + (size_t)(j * 32 + srow) * SS + kk0 + schunk * 8;
      __builtin_amdgcn_global_load_lds(
          (const __attribute__((address_space(1))) void*)gk,
          (__attribute__((address_space(3))) void*)(sm + buf * 8192 + j * 2048 + w * 512),
          16, 0, 0);
      __builtin_amdgcn_global_load_lds(
          (const __attribute__((address_space(1))) void*)gv,
          (__attribute__((address_space(3))) void*)(sm + buf * 8192 + 4096 + j * 2048 + w * 512),
          16, 0, 0);
    }
  };

  short8 bq[4];
#pragma unroll
  for (int k4 = 0; k4 < 4; ++k4)
    bq[k4] = *reinterpret_cast<const short8*>(
        Qp + (size_t)(q0 + c5) * DHH + k4 * 16 + h * 8);

  STAGE(0, 0);

  f32x16 oa0, oa1;
#pragma unroll
  for (int i = 0; i < 16; ++i) { oa0[i] = 0.f; oa1[i] = 0.f; }
  float m_run = 0.f, l_part = 0.f;

  __syncthreads();

  for (int kt = 0; kt < SS / 64; ++kt) {
    const int buf = kt & 1;
    if (kt + 1 < SS / 64) STAGE(buf ^ 1, kt + 1);

    const unsigned short* Kl = sm + buf * 8192;
    const unsigned short* Vl = Kl + 4096;

    // QK^T with C-init = -m_run (folds the softmax subtraction into MFMA)
    f32x16 st0, st1;
    const float nm = -m_run;
#pragma unroll
    for (int i = 0; i < 16; ++i) { st0[i] = nm; st1[i] = nm; }

    __builtin_amdgcn_s_setprio(1);
#pragma unroll
    for (int k4 = 0; k4 < 4; ++k4) {
      const int pos = ((2 * k4 + h) ^ cx) * 8;
      short8 ak0 = *reinterpret_cast<const short8*>(Kl + c5 * 64 + pos);
      short8 ak1 = *reinterpret_cast<const short8*>(Kl + (32 + c5) * 64 + pos);
      st0 = __builtin_amdgcn_mfma_f32_32x32x16_bf16(ak0, bq[k4], st0, 0, 0, 0);
      st1 = __builtin_amdgcn_mfma_f32_32x32x16_bf16(ak1, bq[k4], st1, 0, 0, 0);
    }
    __builtin_amdgcn_s_setprio(0);

    // balanced v_max3 tree over the lane's 32 offset-scores
    float a0 = m3(st0[0], st0[1], st0[2]);
    float a1 = m3(st0[3], st0[4], st0[5]);
    float a2 = m3(st0[6], st0[7], st0[8]);
    float a3 = m3(st0[9], st0[10], st0[11]);
    float a4 = m3(st0[12], st0[13], st0[14]);
    float a5 = m3(st0[15], st1[0], st1[1]);
    float a6 = m3(st1[2], st1[3], st1[4]);
    float a7 = m3(st1[5], st1[6], st1[7]);
    float a8 = m3(st1[8], st1[9], st1[10]);
    float a9 = m3(st1[11], st1[12], st1[13]);
    float a10 = fmaxf(st1[14], st1[15]);
    float b0 = m3(a0, a1, a2);
    float b1 = m3(a3, a4, a5);
    float b2 = m3(a6, a7, a8);
    float b3 = m3(a9, a10, b0);
    float mloc = m3(b1, b2, b3);
    {
      unsigned ua = __float_as_uint(mloc), ub = ua;
      plswap(ua, ub);
      mloc = fmaxf(__uint_as_float(ua), __uint_as_float(ub));
    }

    if (!__all(mloc <= 11.0f)) {          // defer-max rescale (rare)
      const float d  = fmaxf(mloc, 0.f);
      const float al = exp2f(-d);
      l_part *= al;
#pragma unroll
      for (int i = 0; i < 16; ++i) { oa0[i] *= al; oa1[i] *= al; }
#pragma unroll
      for (int i = 0; i < 16; ++i) { st0[i] -= d; st1[i] -= d; }
      m_run += d;
    }

    float l0 = 0.f, l1 = 0.f, l2 = 0.f, l3 = 0.f;
#pragma unroll
    for (int i = 0; i < 16; i += 4) {
      st0[i]     = fast_exp2(st0[i]);     l0 += st0[i];
      st0[i + 1] = fast_exp2(st0[i + 1]); l1 += st0[i + 1];
      st0[i + 2] = fast_exp2(st0[i + 2]); l2 += st0[i + 2];
      st0[i + 3] = fast_exp2(st0[i + 3]); l3 += st0[i + 3];
      st1[i]     = fast_exp2(st1[i]);     l0 += st1[i];
      st1[i + 1] = fast_exp2(st1[i + 1]); l1 += st1[i + 1];
      st1[i + 2] = fast_exp2(st1[i + 2]); l2 += st1[i + 2];
      st1[i + 3] = fast_exp2(st1[i + 3]); l3 += st1[i + 3];
    }
    l_part += (l0 + l1) + (l2 + l3);

    // pack P to bf16 pairs: pw[M*2+t2] = rows 8M+4h+{2t2,2t2+1}
    unsigned pw[16];
#pragma unroll
    for (int m4 = 0; m4 < 4; ++m4)
#pragma unroll
      for (int t2 = 0; t2 < 2; ++t2) {
        pw[m4 * 2 + t2]     = cvt_pk_bf16(st0[m4 * 4 + 2 * t2], st0[m4 * 4 + 2 * t2 + 1]);
        pw[8 + m4 * 2 + t2] = cvt_pk_bf16(st1[m4 * 4 + 2 * t2], st1[m4 * 4 + 2 * t2 + 1]);
      }

    // PV: one permlane32_swap yields both B-operand words for both halves
    __builtin_amdgcn_s_setprio(1);
#pragma unroll
    for (int ks = 0; ks < 4; ++ks) {
      union { unsigned u[4]; short8 s8; } pbu;
#pragma unroll
      for (int t2 = 0; t2 < 2; ++t2) {
        unsigned a = pw[4 * ks + t2];       // even M = 2ks
        unsigned b = pw[4 * ks + 2 + t2];   // odd  M = 2ks+1
        plswap(a, b);
        pbu.u[t2]     = a;                  // rows 16ks + 8h + {2t2,2t2+1}
        pbu.u[2 + t2] = b;                  // rows 16ks + 8h + 4 + {2t2,2t2+1}
      }
      const int vpos = ((2 * ks + h) ^ cx) * 8;
      short8 av0 = *reinterpret_cast<const short8*>(Vl + c5 * 64 + vpos);
      short8 av1 = *reinterpret_cast<const short8*>(Vl + (32 + c5) * 64 + vpos);
      oa0 = __builtin_amdgcn_mfma_f32_32x32x16_bf16(av0, pbu.s8, oa0, 0, 0, 0);
      oa1 = __builtin_amdgcn_mfma_f32_32x32x16_bf16(av1, pbu.s8, oa1, 0, 0, 0);
    }
    __builtin_amdgcn_s_setprio(0);
    __syncthreads();
  }

  // epilogue
  unsigned la = __float_as_uint(l_part), lb = la;
  plswap(la, lb);
  const float lt  = __uint_as_float(la) + __uint_as_float(lb);
  const float inv = 1.f / lt;
  const int b = bh >> 4, hd = bh & 15;
  float* Orow = O + ((size_t)(b * SS) + q0 + c5) * DD + hd * DHH;
#pragma unroll
  for (int m4 = 0; m4 < 4; ++m4) {
    f32x4 v0, v1;
#pragma unroll
    for (int r = 0; r < 4; ++r) {
      v0[r] = oa0[m4 * 4 + r] * inv;
      v1[r] = oa1[m4 * 4 + r] * inv;
    }
    *reinterpret_cast<f32x4*>(Orow + m4 * 8 + 4 * h)      = v0;
    *reinterpret_cast<f32x4*>(Orow + 32 + m4 * 8 + 4 * h) = v1;
  }
}

extern "C" void kernel_launch(void* const* d_in, const int* in_sizes, int n_in,
                              void* d_out, int out_size, void* d_ws, size_t ws_size,
                              hipStream_t stream) {
  (void)in_sizes; (void)n_in; (void)out_size; (void)ws_size;
  const float* Xq = (const float*)d_in[0];
  const float* Xk = (const float*)d_in[1];
  const float* Xv = (const float*)d_in[2];
  const float* WQ = (const float*)d_in[3];
  const float* bQ = (const float*)d_in[4];
  const float* WK = (const float*)d_in[5];
  const float* bK = (const float*)d_in[6];
  const float* WV = (const float*)d_in[7];
  const float* bV = (const float*)d_in[8];
  float* O = (float*)d_out;

  const size_t elems = (size_t)BB * HH * SS * DHH;   // 8388608
  unsigned short* Qbuf = (unsigned short*)d_ws;
  unsigned short* Kbuf = Qbuf + elems;
  unsigned short* Vbuf = Kbuf + elems;
  unsigned short* Xc   = Vbuf + elems;               // 8388608 elems
  unsigned short* Wc   = Xc + (size_t)XN;            // 1048576 elems

  const float CLOG = 0.125f * 1.4426950408889634f;   // 1/sqrt(DH) * log2(e)
  const int cgrid = (XN + WN) / 8 / 256;             // 4608

  conv_kernel<<<cgrid, 256, 0, stream>>>(Xq, WQ, Xc, Wc);
  proj_kernel<<<512, 256, 0, stream>>>(Xc, Wc, bQ, Qbuf, 0, CLOG);
  conv_kernel<<<cgrid, 256, 0, stream>>>(Xk, WK, Xc, Wc);
  proj_kernel<<<512, 256, 0, stream>>>(Xc, Wc, bK, Kbuf, 1, 1.0f);
  conv_kernel<<<cgrid, 256, 0, stream>>>(Xv, WV, Xc, Wc);
  proj_kernel<<<512, 256, 0, stream>>>(Xc, Wc, bV, Vbuf, 2, 1.0f);

  attn_kernel<<<1024, 256, 0, stream>>>(Qbuf, Kbuf, Vbuf, O);
}